// Round 6
// baseline (93.193 us; speedup 1.0000x reference)
//
#include <hip/hip_runtime.h>
#include <stdint.h>

#define HW    4096      // 64*64
#define CIN   256
#define COUT  512
#define NSPE  64500
#define NFAM  510
#define NORD  100
#define NOUT  65110     // 64500+510+100

typedef __attribute__((ext_vector_type(8))) short bf16x8;
typedef __attribute__((ext_vector_type(4))) float f32x4;
typedef __attribute__((address_space(3))) uint32_t lds_u32;
typedef __attribute__((address_space(1))) const uint32_t glob_u32;

__device__ __forceinline__ short f32_to_bf16(float f) {
    uint32_t u = __float_as_uint(f);
    u += 0x7fffu + ((u >> 16) & 1u);   // RNE
    return (short)(u >> 16);
}
__device__ __forceinline__ float bf16_to_f32(unsigned short s) {
    return __uint_as_float(((uint32_t)s) << 16);
}

// Tile formats (slot-XOR swizzle, self-inverse):
//  Wt: [mat*4+mt][kt][128m x 32k] tiles (8KB), elem (m,k): m*32 + ((ks^((m>>1)&3))<<3)+(k&7)
//  Xt: [b*64+nt][kt][64n x 32k] tiles (4KB), elem (n,k): n*32 + ((ks^((n>>1)&3))<<3)+(k&7)

// ---- unified convert: z<4 -> x panels (batch z), z==4 -> weights ----
__global__ __launch_bounds__(256) void convert_kernel(
    const float* __restrict__ x,
    const float* __restrict__ wq, const float* __restrict__ wk,
    const float* __restrict__ wv,
    short* __restrict__ Xt, short* __restrict__ Wt)
{
    const int t = threadIdx.x;

    if (blockIdx.z < 4) {
        // x: one [64n x 32k] tile per block
        const int kt = blockIdx.x, nt = blockIdx.y, b = blockIdx.z;
        __shared__ float lds[32][65];
        #pragma unroll
        for (int j = 0; j < 8; ++j) {
            int idx = j * 256 + t;
            int c = idx >> 6, p = idx & 63;
            lds[c][p] = x[((size_t)b * CIN + kt * 32 + c) * HW + nt * 64 + p];
        }
        __syncthreads();

        short* out = Xt + (((size_t)(b * 64 + nt) * 8 + kt) << 11);
        union { short s[8]; int4 v; } pk;
        const int n = t >> 2;                    // e = t*8+j: n fixed per thread
        const int sp = t & 3;
        const int k0 = (sp ^ ((n >> 1) & 3)) << 3;
        #pragma unroll
        for (int j = 0; j < 8; ++j)
            pk.s[j] = f32_to_bf16(lds[k0 + j][n]);
        *(int4*)(out + t * 8) = pk.v;
    } else {
        // W: one [128m x 32k] tile per block (y = mat*4+mt in 0..11)
        if (blockIdx.y >= 12) return;
        const int kt = blockIdx.x, mt = blockIdx.y & 3, mat = blockIdx.y >> 2;
        const float* __restrict__ W = (mat == 0) ? wq : (mat == 1) ? wk : wv;
        const int m = t >> 1;
        short* out = Wt + (((size_t)(mat * 4 + mt) * 8 + kt) << 12);

        union { short s[16]; int4 v[2]; } pk;
        #pragma unroll
        for (int j = 0; j < 16; ++j) {
            int e  = t * 16 + j;
            int sp = (e >> 3) & 3;
            int i  = e & 7;
            int k  = ((sp ^ ((m >> 1) & 3)) << 3) + i;
            pk.s[j] = f32_to_bf16(W[(size_t)(mt * 128 + m) * CIN + kt * 32 + k]);
        }
        int4* dst = (int4*)(out + t * 16);
        dst[0] = pk.v[0];
        dst[1] = pk.v[1];
    }
}

// ---- QKV GEMM v2: K-resident B ----
// block = (nt, b, half): B[64n x 256k] resident in LDS (32KB);
// loop 6 (mat,mt) x 8 kt with A[128m x 32k] double-buffered (16KB).
// 2 waves: wave wv owns m-rows [wv*64, wv*64+64). Per kt: 8 ds_read_b128, 16 MFMA.
__global__ __launch_bounds__(128, 2) void qkv_mfma_kernel(
    const short* __restrict__ Wt, const short* __restrict__ Xt,
    const float* __restrict__ bq, const float* __restrict__ bk,
    const float* __restrict__ bv, short* __restrict__ qkv)
{
    const int nt = blockIdx.x, b = blockIdx.y, half = blockIdx.z;
    const short* Bt = Xt + (((size_t)(b * 64 + nt) * 8) << 11);   // 8 x 4KB tiles

    __shared__ __align__(16) short Bs[16384];     // 64n x 256k (8 kt-tiles)
    __shared__ __align__(16) short As[2][4096];   // 128m x 32k, dbuf

    const int tid = threadIdx.x, lane = tid & 63, wv = tid >> 6;
    const int l15 = lane & 15, sl = lane >> 4;
    const int sw = ((sl ^ ((l15 >> 1) & 3)) << 3);

    // stage resident B: 32KB
    #pragma unroll
    for (int i = 0; i < 16; ++i)
        __builtin_amdgcn_global_load_lds(
            (glob_u32*)(Bt + i * 1024 + tid * 8),
            (lds_u32*)(Bs + i * 1024 + tid * 8), 16, 0, 0);

#define STAGE_A(MM, KT, BUF) do {                                             \
    int mt_ = half * 2 + (MM) / 3, mat_ = (MM) % 3;                           \
    const short* tile_ = Wt + (((size_t)(mat_ * 4 + mt_) * 8 + (KT)) << 12);  \
    _Pragma("unroll")                                                         \
    for (int i_ = 0; i_ < 4; ++i_)                                            \
        __builtin_amdgcn_global_load_lds(                                     \
            (glob_u32*)(tile_ + i_ * 1024 + tid * 8),                         \
            (lds_u32*)(&As[BUF][i_ * 1024 + tid * 8]), 16, 0, 0);             \
} while (0)

    STAGE_A(0, 0, 0);
    __syncthreads();

    int buf = 0;
    for (int mm = 0; mm < 6; ++mm) {
        f32x4 acc[4][4] = {};
        #pragma unroll
        for (int kt = 0; kt < 8; ++kt) {
            // prefetch next A-tile
            if (kt < 7)       STAGE_A(mm, kt + 1, buf ^ 1);
            else if (mm < 5)  STAGE_A(mm + 1, 0, buf ^ 1);

            bf16x8 a[4], bb[4];
            #pragma unroll
            for (int f = 0; f < 4; ++f)
                a[f] = *(const bf16x8*)(&As[buf][(wv * 64 + f * 16 + l15) * 32 + sw]);
            #pragma unroll
            for (int f = 0; f < 4; ++f)
                bb[f] = *(const bf16x8*)(&Bs[kt * 2048 + (f * 16 + l15) * 32 + sw]);

            #pragma unroll
            for (int mf = 0; mf < 4; ++mf)
                #pragma unroll
                for (int nf = 0; nf < 4; ++nf)
                    acc[mf][nf] = __builtin_amdgcn_mfma_f32_16x16x32_bf16(
                        a[mf], bb[nf], acc[mf][nf], 0, 0, 0);
            __syncthreads();
            buf ^= 1;
        }

        // epilogue for this (mat, mt)
        const int mt = half * 2 + mm / 3, mat = mm % 3;
        const float* bias = (mat == 0) ? bq : (mat == 1) ? bk : bv;
        short* out = qkv + (((size_t)(b * 3 + mat) * COUT + mt * 128) * HW) + nt * 64;
        const int col = lane & 15, g = lane >> 4;
        #pragma unroll
        for (int mf = 0; mf < 4; ++mf) {
            #pragma unroll
            for (int r = 0; r < 4; ++r) {
                int m = wv * 64 + mf * 16 + g * 4 + r;
                float bsv = bias[mt * 128 + m];
                #pragma unroll
                for (int nf = 0; nf < 4; ++nf)
                    out[(size_t)m * HW + nf * 16 + col] =
                        f32_to_bf16(acc[mf][nf][r] + bsv);
            }
        }
    }
#undef STAGE_A
}

// ---- attention + relu + pool: one block per (channel, batch) ----
__global__ __launch_bounds__(256) void attn_pool_kernel(
    const unsigned short* __restrict__ qkv,
    const float* __restrict__ rel_h, const float* __restrict__ rel_w,
    float* __restrict__ pooled)   // [4][COUT]
{
    const int c = blockIdx.x;
    const int b = blockIdx.y;
    const int tid = threadIdx.x;
    const int h  = tid >> 2;            // 0..63
    const int w0 = (tid & 3) * 16;      // 0,16,32,48

    const unsigned short* qc = qkv + ((size_t)(b * 3 + 0) * COUT + c) * HW;
    const unsigned short* kg = qkv + ((size_t)(b * 3 + 1) * COUT + c) * HW;
    const unsigned short* vg = qkv + ((size_t)(b * 3 + 2) * COUT + c) * HW;

    __shared__ float kS[66 * 67];
    __shared__ float vS[66 * 67];

    if (tid < 67) {
        kS[tid] = 0.f;            vS[tid] = 0.f;             // row -1
        kS[65 * 67 + tid] = 0.f;  vS[65 * 67 + tid] = 0.f;   // row 64
    }
    if (tid < 64) {
        int r0 = (tid + 1) * 67;
        kS[r0] = 0.f;       vS[r0] = 0.f;                    // col -1
        kS[r0 + 65] = 0.f;  vS[r0 + 65] = 0.f;               // col 64
    }

    #pragma unroll
    for (int it = 0; it < 2; ++it) {
        int ch = tid + it * 256;
        int y = ch >> 3, xs = (ch & 7) * 8;
        union { int4 v; unsigned short s[8]; } ak, av;
        ak.v = reinterpret_cast<const int4*>(kg)[ch];
        av.v = reinterpret_cast<const int4*>(vg)[ch];
        float* kp = &kS[(y + 1) * 67 + xs + 1];
        float* vp = &vS[(y + 1) * 67 + xs + 1];
        #pragma unroll
        for (int e = 0; e < 8; ++e) {
            kp[e] = bf16_to_f32(ak.s[e]);
            vp[e] = bf16_to_f32(av.s[e]);
        }
    }

    union { unsigned short s[16]; int4 v[2]; } qr;
    qr.v[0] = reinterpret_cast<const int4*>(qc + h * 64 + w0)[0];
    qr.v[1] = reinterpret_cast<const int4*>(qc + h * 64 + w0)[1];
    float qf[16];
    #pragma unroll
    for (int i = 0; i < 16; ++i)
        qf[i] = bf16_to_f32(qr.s[i]) * 1.4426950408889634f;

    const bool isH = (c < 256);
    float r3[3];
    #pragma unroll
    for (int i = 0; i < 3; ++i)
        r3[i] = isH ? rel_h[c * 3 + i] : rel_w[(c - 256) * 3 + i];
    float relv[9];
    #pragma unroll
    for (int kh = 0; kh < 3; ++kh)
        #pragma unroll
        for (int kw = 0; kw < 3; ++kw)
            relv[kh * 3 + kw] = isH ? r3[kh] : r3[kw];

    __syncthreads();

    const float* krow = &kS[h * 67 + w0];
    const float* vrow = &vS[h * 67 + w0];

    float kcw[3][3], vcw[3][3];
    #pragma unroll
    for (int s = 0; s < 2; ++s)
        #pragma unroll
        for (int r = 0; r < 3; ++r) {
            kcw[s][r] = krow[r * 67 + s];
            vcw[s][r] = vrow[r * 67 + s];
        }

    float total = 0.f;
    #pragma unroll
    for (int i = 0; i < 16; ++i) {
        const int s2 = (i + 2) % 3;
        #pragma unroll
        for (int r = 0; r < 3; ++r) {
            kcw[s2][r] = krow[r * 67 + i + 2];
            vcw[s2][r] = vrow[r * 67 + i + 2];
        }
        const float q2 = qf[i];
        float num = 0.f, den = 0.f;
        #pragma unroll
        for (int r = 0; r < 3; ++r)
            #pragma unroll
            for (int dx = 0; dx < 3; ++dx) {
                const int sl = (i + dx) % 3;
                float e = __builtin_exp2f(q2 * (kcw[sl][r] + relv[r * 3 + dx]));
                den += e;
                num = fmaf(e, vcw[sl][r], num);
            }
        total += fmaxf(num * __builtin_amdgcn_rcpf(den), 0.f);
    }

    #pragma unroll
    for (int off = 32; off; off >>= 1) total += __shfl_down(total, off);
    __shared__ float red[4];
    if ((tid & 63) == 0) red[tid >> 6] = total;
    __syncthreads();
    if (tid == 0)
        pooled[b * COUT + c] = (red[0] + red[1] + red[2] + red[3]) * (1.f / 4096.f);
}

// ---- classifier heads ----
__global__ __launch_bounds__(256) void heads_kernel(
    const float* __restrict__ pooled,    // [4][COUT]
    const float* __restrict__ w_sp, const float* __restrict__ b_sp,
    const float* __restrict__ w_fa, const float* __restrict__ b_fa,
    const float* __restrict__ w_or, const float* __restrict__ b_or,
    float* __restrict__ out)             // [4][NOUT]
{
    const int lane   = threadIdx.x & 63;
    const int wave   = blockIdx.x * (blockDim.x >> 6) + (threadIdx.x >> 6);
    const int nwaves = gridDim.x * (blockDim.x >> 6);

    float pr[4][8];
    #pragma unroll
    for (int b = 0; b < 4; ++b)
        #pragma unroll
        for (int e = 0; e < 8; ++e)
            pr[b][e] = pooled[b * COUT + lane * 8 + e];

    for (int j = wave; j < NOUT; j += nwaves) {
        const float* __restrict__ wrow;
        float bias;
        if (j < NSPE)            { wrow = w_sp + (size_t)j * COUT;          bias = b_sp[j]; }
        else if (j < NSPE + NFAM){ wrow = w_fa + (size_t)(j - NSPE) * COUT; bias = b_fa[j - NSPE]; }
        else                     { wrow = w_or + (size_t)(j - NSPE - NFAM) * COUT; bias = b_or[j - NSPE - NFAM]; }

        const float4 w0 = reinterpret_cast<const float4*>(wrow)[lane * 2 + 0];
        const float4 w1 = reinterpret_cast<const float4*>(wrow)[lane * 2 + 1];
        const float we[8] = {w0.x, w0.y, w0.z, w0.w, w1.x, w1.y, w1.z, w1.w};

        float a0 = 0.f, a1 = 0.f, a2 = 0.f, a3 = 0.f;
        #pragma unroll
        for (int e = 0; e < 8; ++e) {
            a0 += we[e] * pr[0][e];
            a1 += we[e] * pr[1][e];
            a2 += we[e] * pr[2][e];
            a3 += we[e] * pr[3][e];
        }
        #pragma unroll
        for (int off = 32; off; off >>= 1) {
            a0 += __shfl_down(a0, off);
            a1 += __shfl_down(a1, off);
            a2 += __shfl_down(a2, off);
            a3 += __shfl_down(a3, off);
        }
        if (lane == 0) {
            out[0 * NOUT + j] = a0 + bias;
            out[1 * NOUT + j] = a1 + bias;
            out[2 * NOUT + j] = a2 + bias;
            out[3 * NOUT + j] = a3 + bias;
        }
    }
}

extern "C" void kernel_launch(void* const* d_in, const int* in_sizes, int n_in,
                              void* d_out, int out_size, void* d_ws, size_t ws_size,
                              hipStream_t stream) {
    const float* x     = (const float*)d_in[0];
    const float* wq    = (const float*)d_in[1];
    const float* bq    = (const float*)d_in[2];
    const float* wk    = (const float*)d_in[3];
    const float* bk    = (const float*)d_in[4];
    const float* wv    = (const float*)d_in[5];
    const float* bv    = (const float*)d_in[6];
    const float* rel_h = (const float*)d_in[7];
    const float* rel_w = (const float*)d_in[8];
    const float* w_sp  = (const float*)d_in[9];
    const float* b_sp  = (const float*)d_in[10];
    const float* w_fa  = (const float*)d_in[11];
    const float* b_fa  = (const float*)d_in[12];
    const float* w_or  = (const float*)d_in[13];
    const float* b_or  = (const float*)d_in[14];
    float* out = (float*)d_out;

    // ws: Wt bf16 | Xt bf16 | qkv bf16 | pooled f32
    short* Wt  = (short*)d_ws;                       // 3*512*256   = 393216
    short* Xt  = Wt + 393216;                        // 4*256*4096  = 4194304
    short* qkv = Xt + 4194304;                       // 4*3*512*4096= 25165824
    float* pooled = (float*)(qkv + 25165824);        // 4*512

    convert_kernel<<<dim3(8, 64, 5), 256, 0, stream>>>(x, wq, wk, wv, Xt, Wt);
    qkv_mfma_kernel<<<dim3(64, 4, 2), 128, 0, stream>>>(Wt, Xt, bq, bk, bv, qkv);
    attn_pool_kernel<<<dim3(COUT, 4), 256, 0, stream>>>(
        (const unsigned short*)qkv, rel_h, rel_w, pooled);
    heads_kernel<<<dim3(2048), 256, 0, stream>>>(
        pooled, w_sp, b_sp, w_fa, b_fa, w_or, b_or, out);
}

// Round 7
// 83.353 us; speedup vs baseline: 1.1181x; 1.1181x over previous
//
#include <hip/hip_runtime.h>
#include <stdint.h>

#define HW    4096      // 64*64
#define CIN   256
#define COUT  512
#define NSPE  64500
#define NFAM  510
#define NORD  100
#define NOUT  65110     // 64500+510+100

typedef __attribute__((ext_vector_type(8))) short bf16x8;
typedef __attribute__((ext_vector_type(4))) float f32x4;
typedef __attribute__((address_space(3))) uint32_t lds_u32;
typedef __attribute__((address_space(1))) const uint32_t glob_u32;

__device__ __forceinline__ short f32_to_bf16(float f) {
    uint32_t u = __float_as_uint(f);
    u += 0x7fffu + ((u >> 16) & 1u);   // RNE
    return (short)(u >> 16);
}
__device__ __forceinline__ float bf16_to_f32(unsigned short s) {
    return __uint_as_float(((uint32_t)s) << 16);
}

// Tile layout: [128 rows][32 k] bf16, element (row,k) stored at
//   row*32 + ((k>>3 ^ ((row>>1)&3))<<3) + (k&7)     (slot-XOR swizzle)

// ---- unified convert: z<4 -> x slices (batch z), z==4 -> weights ----
__global__ __launch_bounds__(256) void convert_kernel(
    const float* __restrict__ x,
    const float* __restrict__ wq, const float* __restrict__ wk,
    const float* __restrict__ wv,
    short* __restrict__ Xt, short* __restrict__ Wt)
{
    const int t = threadIdx.x;
    __shared__ float lds[32][128];

    if (blockIdx.z < 4) {
        const int kt = blockIdx.x, nt = blockIdx.y, b = blockIdx.z;
        #pragma unroll
        for (int j = 0; j < 16; ++j) {
            int idx = j * 256 + t;
            int c = idx >> 7, p = idx & 127;
            lds[c][p] = x[((size_t)b * CIN + kt * 32 + c) * HW + nt * 128 + p];
        }
        __syncthreads();

        const int n = t >> 1;
        short* out = Xt + (((size_t)(b * 32 + nt) * 8 + kt) << 12);
        union { short s[16]; int4 v[2]; } pk;
        #pragma unroll
        for (int j = 0; j < 16; ++j) {
            int e  = t * 16 + j;
            int sp = (e >> 3) & 3;
            int i  = e & 7;
            int k  = ((sp ^ ((n >> 1) & 3)) << 3) + i;
            pk.s[j] = f32_to_bf16(lds[k][n]);
        }
        int4* dst = (int4*)(out + t * 16);
        dst[0] = pk.v[0];
        dst[1] = pk.v[1];
    } else {
        if (blockIdx.y >= 12) return;
        const int kt = blockIdx.x, mt = blockIdx.y & 3, mat = blockIdx.y >> 2;
        const float* __restrict__ W = (mat == 0) ? wq : (mat == 1) ? wk : wv;
        const int m = t >> 1;
        short* out = Wt + (((size_t)(mat * 4 + mt) * 8 + kt) << 12);

        union { short s[16]; int4 v[2]; } pk;
        #pragma unroll
        for (int j = 0; j < 16; ++j) {
            int e  = t * 16 + j;
            int sp = (e >> 3) & 3;
            int i  = e & 7;
            int k  = ((sp ^ ((m >> 1) & 3)) << 3) + i;
            pk.s[j] = f32_to_bf16(W[(size_t)(mt * 128 + m) * CIN + kt * 32 + k]);
        }
        int4* dst = (int4*)(out + t * 16);
        dst[0] = pk.v[0];
        dst[1] = pk.v[1];
    }
}

// ---- QKV GEMM (R4 config: BM=BN=128, BK=32, 4 waves 2x2, dbuf) ----
__global__ __launch_bounds__(256) void qkv_mfma_kernel(
    const short* __restrict__ Wt, const short* __restrict__ Xt,
    const float* __restrict__ bq, const float* __restrict__ bk,
    const float* __restrict__ bv, short* __restrict__ qkv)
{
    const int nt = blockIdx.x, mt = blockIdx.y, z = blockIdx.z;
    const int mat = z >> 2, b = z & 3;
    const short* At = Wt + (((size_t)(mat * 4 + mt) * 8) << 12);
    const short* Bt = Xt + (((size_t)(b * 32 + nt) * 8) << 12);

    __shared__ __align__(16) short As[2][4096];
    __shared__ __align__(16) short Bs[2][4096];

    const int tid = threadIdx.x, lane = tid & 63, wid = tid >> 6;
    const int wm = wid >> 1, wn = wid & 1;
    const int l15 = lane & 15, sl = lane >> 4;
    const int sw = ((sl ^ ((l15 >> 1) & 3)) << 3);

    f32x4 acc[4][4] = {};

#define STAGE(KT, BUF) do {                                                   \
    _Pragma("unroll")                                                         \
    for (int j = 0; j < 4; ++j) {                                             \
        int li = wid * 4 + j;                                                 \
        if (li < 8)                                                           \
            __builtin_amdgcn_global_load_lds(                                 \
                (glob_u32*)(At + (KT) * 4096 + li * 512 + lane * 8),          \
                (lds_u32*)(&As[BUF][li * 512]), 16, 0, 0);                    \
        else                                                                  \
            __builtin_amdgcn_global_load_lds(                                 \
                (glob_u32*)(Bt + (KT) * 4096 + (li - 8) * 512 + lane * 8),    \
                (lds_u32*)(&Bs[BUF][(li - 8) * 512]), 16, 0, 0);              \
    }                                                                         \
} while (0)

    STAGE(0, 0);
    __syncthreads();

    int buf = 0;
    #pragma unroll 2
    for (int kt = 0; kt < 8; ++kt) {
        if (kt < 7) STAGE(kt + 1, buf ^ 1);

        bf16x8 a[4], bb[4];
        #pragma unroll
        for (int f = 0; f < 4; ++f) {
            int ra = wm * 64 + f * 16 + l15;
            a[f]  = *(const bf16x8*)(&As[buf][ra * 32 + sw]);
            int rb = wn * 64 + f * 16 + l15;
            bb[f] = *(const bf16x8*)(&Bs[buf][rb * 32 + sw]);
        }
        #pragma unroll
        for (int mf = 0; mf < 4; ++mf)
            #pragma unroll
            for (int nf = 0; nf < 4; ++nf)
                acc[mf][nf] = __builtin_amdgcn_mfma_f32_16x16x32_bf16(
                    a[mf], bb[nf], acc[mf][nf], 0, 0, 0);
        __syncthreads();
        buf ^= 1;
    }
#undef STAGE

    const float* bias = (mat == 0) ? bq : (mat == 1) ? bk : bv;
    short* out = qkv + (((size_t)(b * 3 + mat) * COUT + mt * 128) * HW) + nt * 128;
    const int col = lane & 15, g = lane >> 4;
    #pragma unroll
    for (int mf = 0; mf < 4; ++mf) {
        #pragma unroll
        for (int nf = 0; nf < 4; ++nf) {
            #pragma unroll
            for (int r = 0; r < 4; ++r) {
                int m = wm * 64 + mf * 16 + g * 4 + r;
                int n = wn * 64 + nf * 16 + col;
                float val = acc[mf][nf][r] + bias[mt * 128 + m];
                out[(size_t)m * HW + n] = f32_to_bf16(val);
            }
        }
    }
}

// ---- attention + relu + pool: one block per CHANNEL, pipelined b-loop ----
// b+1 k/v/q loaded to regs at iter start (hidden under compute of b),
// written to kS/vS[buf^1] after compute; ONE barrier per iteration.
__global__ __launch_bounds__(256) void attn_pool_kernel(
    const unsigned short* __restrict__ qkv,
    const float* __restrict__ rel_h, const float* __restrict__ rel_w,
    float* __restrict__ pooled)   // [4][COUT]
{
    const int c = blockIdx.x;
    const int tid = threadIdx.x;
    const int h  = tid >> 2;            // 0..63
    const int w0 = (tid & 3) * 16;      // 0,16,32,48

    __shared__ float kS[2][66 * 67];
    __shared__ float vS[2][66 * 67];
    __shared__ float red[4][4];

    // zero pad borders of BOTH buffers (written once, never overwritten)
    #pragma unroll
    for (int bu = 0; bu < 2; ++bu) {
        if (tid < 67) {
            kS[bu][tid] = 0.f;            vS[bu][tid] = 0.f;
            kS[bu][65 * 67 + tid] = 0.f;  vS[bu][65 * 67 + tid] = 0.f;
        }
        if (tid < 64) {
            int r0 = (tid + 1) * 67;
            kS[bu][r0] = 0.f;       vS[bu][r0] = 0.f;
            kS[bu][r0 + 65] = 0.f;  vS[bu][r0 + 65] = 0.f;
        }
    }

    const bool isH = (c < 256);
    float r3[3];
    #pragma unroll
    for (int i = 0; i < 3; ++i)
        r3[i] = isH ? rel_h[c * 3 + i] : rel_w[(c - 256) * 3 + i];
    float relv[9];
    #pragma unroll
    for (int kh = 0; kh < 3; ++kh)
        #pragma unroll
        for (int kw = 0; kw < 3; ++kw)
            relv[kh * 3 + kw] = isH ? r3[kh] : r3[kw];

    const int y0 = tid >> 3,         xs0 = (tid & 7) * 8;
    const int y1 = (tid + 256) >> 3, xs1 = ((tid + 256) & 7) * 8;

    int4 krg0, krg1, vrg0, vrg1, qn0, qn1;
#define LOADB(B) do {                                                         \
    const unsigned short* kg_ = qkv + ((size_t)((B) * 3 + 1) * COUT + c) * HW;\
    const unsigned short* vg_ = qkv + ((size_t)((B) * 3 + 2) * COUT + c) * HW;\
    const unsigned short* qc_ = qkv + ((size_t)((B) * 3 + 0) * COUT + c) * HW;\
    krg0 = reinterpret_cast<const int4*>(kg_)[tid];                           \
    krg1 = reinterpret_cast<const int4*>(kg_)[tid + 256];                     \
    vrg0 = reinterpret_cast<const int4*>(vg_)[tid];                           \
    vrg1 = reinterpret_cast<const int4*>(vg_)[tid + 256];                     \
    qn0  = reinterpret_cast<const int4*>(qc_ + h * 64 + w0)[0];               \
    qn1  = reinterpret_cast<const int4*>(qc_ + h * 64 + w0)[1];               \
} while (0)

#define WRITEB(BUF) do {                                                      \
    union { int4 v; unsigned short s[8]; } ak_, av_;                          \
    ak_.v = krg0; av_.v = vrg0;                                               \
    _Pragma("unroll")                                                         \
    for (int e = 0; e < 8; ++e) {                                             \
        kS[BUF][(y0 + 1) * 67 + xs0 + 1 + e] = bf16_to_f32(ak_.s[e]);         \
        vS[BUF][(y0 + 1) * 67 + xs0 + 1 + e] = bf16_to_f32(av_.s[e]);         \
    }                                                                         \
    ak_.v = krg1; av_.v = vrg1;                                               \
    _Pragma("unroll")                                                         \
    for (int e = 0; e < 8; ++e) {                                             \
        kS[BUF][(y1 + 1) * 67 + xs1 + 1 + e] = bf16_to_f32(ak_.s[e]);         \
        vS[BUF][(y1 + 1) * 67 + xs1 + 1 + e] = bf16_to_f32(av_.s[e]);         \
    }                                                                         \
} while (0)

    LOADB(0);
    WRITEB(0);

    #pragma unroll
    for (int b = 0; b < 4; ++b) {
        const int buf = b & 1;

        // q for this batch (extract before qn regs are reloaded)
        float qf[16];
        {
            union { int4 v[2]; unsigned short s[16]; } qu;
            qu.v[0] = qn0; qu.v[1] = qn1;
            #pragma unroll
            for (int i = 0; i < 16; ++i)
                qf[i] = bf16_to_f32(qu.s[i]) * 1.4426950408889634f;
        }

        // issue next batch's loads (fly under compute)
        if (b < 3) LOADB(b + 1);

        __syncthreads();   // buf's write (prologue / prev iter) visible

        const float* krow = &kS[buf][h * 67 + w0];
        const float* vrow = &vS[buf][h * 67 + w0];

        float kcw[3][3], vcw[3][3];
        #pragma unroll
        for (int s = 0; s < 2; ++s)
            #pragma unroll
            for (int r = 0; r < 3; ++r) {
                kcw[s][r] = krow[r * 67 + s];
                vcw[s][r] = vrow[r * 67 + s];
            }

        float total = 0.f;
        #pragma unroll
        for (int i = 0; i < 16; ++i) {
            const int s2 = (i + 2) % 3;
            #pragma unroll
            for (int r = 0; r < 3; ++r) {
                kcw[s2][r] = krow[r * 67 + i + 2];
                vcw[s2][r] = vrow[r * 67 + i + 2];
            }
            const float q2 = qf[i];
            float num = 0.f, den = 0.f;
            #pragma unroll
            for (int r = 0; r < 3; ++r)
                #pragma unroll
                for (int dx = 0; dx < 3; ++dx) {
                    const int sl = (i + dx) % 3;
                    float e = __builtin_exp2f(q2 * (kcw[sl][r] + relv[r * 3 + dx]));
                    den += e;
                    num = fmaf(e, vcw[sl][r], num);
                }
            total += fmaxf(num * __builtin_amdgcn_rcpf(den), 0.f);
        }

        // stage next batch into the other buffer (waits on its global loads)
        if (b < 3) WRITEB(buf ^ 1);

        #pragma unroll
        for (int off = 32; off; off >>= 1) total += __shfl_down(total, off);
        if ((tid & 63) == 0) red[b][tid >> 6] = total;
        // next iter's barrier orders red-write vs final read; buf^1 write vs its readers
    }
#undef LOADB
#undef WRITEB

    __syncthreads();
    if (tid < 4)
        pooled[tid * COUT + c] =
            (red[tid][0] + red[tid][1] + red[tid][2] + red[tid][3]) * (1.f / 4096.f);
}

// ---- classifier heads ----
__global__ __launch_bounds__(256) void heads_kernel(
    const float* __restrict__ pooled,    // [4][COUT]
    const float* __restrict__ w_sp, const float* __restrict__ b_sp,
    const float* __restrict__ w_fa, const float* __restrict__ b_fa,
    const float* __restrict__ w_or, const float* __restrict__ b_or,
    float* __restrict__ out)             // [4][NOUT]
{
    const int lane   = threadIdx.x & 63;
    const int wave   = blockIdx.x * (blockDim.x >> 6) + (threadIdx.x >> 6);
    const int nwaves = gridDim.x * (blockDim.x >> 6);

    float pr[4][8];
    #pragma unroll
    for (int b = 0; b < 4; ++b)
        #pragma unroll
        for (int e = 0; e < 8; ++e)
            pr[b][e] = pooled[b * COUT + lane * 8 + e];

    for (int j = wave; j < NOUT; j += nwaves) {
        const float* __restrict__ wrow;
        float bias;
        if (j < NSPE)            { wrow = w_sp + (size_t)j * COUT;          bias = b_sp[j]; }
        else if (j < NSPE + NFAM){ wrow = w_fa + (size_t)(j - NSPE) * COUT; bias = b_fa[j - NSPE]; }
        else                     { wrow = w_or + (size_t)(j - NSPE - NFAM) * COUT; bias = b_or[j - NSPE - NFAM]; }

        const float4 w0 = reinterpret_cast<const float4*>(wrow)[lane * 2 + 0];
        const float4 w1 = reinterpret_cast<const float4*>(wrow)[lane * 2 + 1];
        const float we[8] = {w0.x, w0.y, w0.z, w0.w, w1.x, w1.y, w1.z, w1.w};

        float a0 = 0.f, a1 = 0.f, a2 = 0.f, a3 = 0.f;
        #pragma unroll
        for (int e = 0; e < 8; ++e) {
            a0 += we[e] * pr[0][e];
            a1 += we[e] * pr[1][e];
            a2 += we[e] * pr[2][e];
            a3 += we[e] * pr[3][e];
        }
        #pragma unroll
        for (int off = 32; off; off >>= 1) {
            a0 += __shfl_down(a0, off);
            a1 += __shfl_down(a1, off);
            a2 += __shfl_down(a2, off);
            a3 += __shfl_down(a3, off);
        }
        if (lane == 0) {
            out[0 * NOUT + j] = a0 + bias;
            out[1 * NOUT + j] = a1 + bias;
            out[2 * NOUT + j] = a2 + bias;
            out[3 * NOUT + j] = a3 + bias;
        }
    }
}

extern "C" void kernel_launch(void* const* d_in, const int* in_sizes, int n_in,
                              void* d_out, int out_size, void* d_ws, size_t ws_size,
                              hipStream_t stream) {
    const float* x     = (const float*)d_in[0];
    const float* wq    = (const float*)d_in[1];
    const float* bq    = (const float*)d_in[2];
    const float* wk    = (const float*)d_in[3];
    const float* bk    = (const float*)d_in[4];
    const float* wv    = (const float*)d_in[5];
    const float* bv    = (const float*)d_in[6];
    const float* rel_h = (const float*)d_in[7];
    const float* rel_w = (const float*)d_in[8];
    const float* w_sp  = (const float*)d_in[9];
    const float* b_sp  = (const float*)d_in[10];
    const float* w_fa  = (const float*)d_in[11];
    const float* b_fa  = (const float*)d_in[12];
    const float* w_or  = (const float*)d_in[13];
    const float* b_or  = (const float*)d_in[14];
    float* out = (float*)d_out;

    // ws: Wt bf16 | Xt bf16 | qkv bf16 | pooled f32
    short* Wt  = (short*)d_ws;                       // 3*512*256   = 393216
    short* Xt  = Wt + 393216;                        // 4*256*4096  = 4194304
    short* qkv = Xt + 4194304;                       // 4*3*512*4096= 25165824
    float* pooled = (float*)(qkv + 25165824);        // 4*512

    convert_kernel<<<dim3(8, 32, 5), 256, 0, stream>>>(x, wq, wk, wv, Xt, Wt);
    qkv_mfma_kernel<<<dim3(32, 4, 12), 256, 0, stream>>>(Wt, Xt, bq, bk, bv, qkv);
    attn_pool_kernel<<<dim3(COUT), 256, 0, stream>>>(
        (const unsigned short*)qkv, rel_h, rel_w, pooled);
    heads_kernel<<<dim3(2048), 256, 0, stream>>>(
        pooled, w_sp, b_sp, w_fa, b_fa, w_or, b_or, out);
}